// Round 7
// baseline (7011.852 us; speedup 1.0000x reference)
//
#include <hip/hip_runtime.h>

#define B_    64
#define T_    1024
#define IN_   64
#define H_    512
#define OUT_  64
#define SLOTS 8
#define HSLOT (64*512)   // elements per h slot
#define NWG   66

typedef _Float16 f16;
typedef _Float16 half8 __attribute__((ext_vector_type(8)));
typedef float    floatx4 __attribute__((ext_vector_type(4)));
typedef unsigned int u32;
typedef unsigned long long u64;

#define MFMA16(a,b,c) __builtin_amdgcn_mfma_f32_16x16x32_f16((a),(b),(c),0,0,0)

// LDS layout (153600 B, 1 WG/CU)
#define H1S_OFF  0        // 32KB: h1 stage (L1/L2); h2 stage (head)
#define H2S_OFF  32768    // 32KB: h2 stage (L2 pass B)
#define RED_OFF  65536    // 64KB: 4 kq-regions x 16KB gate partials
#define XS_OFF   131072   // 16KB: L1 x double-buffer (2 x 8KB fp32)
#define CC_OFF   147456   // 4KB c-state (32b x 32j fp32)
#define PUB_OFF  151552   // 2KB h-publish staging (1024 f16)

__device__ __forceinline__ float sigmoidf_(float x) {
    return 1.0f / (1.0f + __expf(-x));
}
__device__ __forceinline__ float tanhf_(float x) {
    float ax = fabsf(x);
    float e  = __expf(-2.0f * ax);
    float t  = (1.0f - e) / (1.0f + e);
    return x >= 0.0f ? t : -t;
}

// ---- sync primitives (protocol proven R5/R6) ----
// Detect: wave 0 polls 16 per-producer slots (one 64B line) + ballot.
__device__ __forceinline__ void wait16(const u32* base, int lane) {
    for (;;) {
        u32 v = __hip_atomic_load(base + (lane & 15), __ATOMIC_RELAXED, __HIP_MEMORY_SCOPE_AGENT);
        if (__ballot(v != 0) == ~0ull) return;
        __builtin_amdgcn_s_sleep(1);
    }
}
__device__ __forceinline__ void wait1(const u32* p) {
    while (__hip_atomic_load(p, __ATOMIC_RELAXED, __HIP_MEMORY_SCOPE_AGENT) == 0)
        __builtin_amdgcn_s_sleep(1);
}
// Producer flag: RMW executes at IF$; issued after publish-drain barrier.
__device__ __forceinline__ void flag_set(u32* p) {
    (void)__hip_atomic_exchange(p, 1u, __ATOMIC_RELAXED, __HIP_MEMORY_SCOPE_AGENT);
}
// Data reads: system-scope relaxed (sc0+sc1 -> IF$ coherence point). Proven R5.
__device__ __forceinline__ u64 aload8(const f16* p) {
    return __hip_atomic_load((const u64*)p, __ATOMIC_RELAXED, __HIP_MEMORY_SCOPE_SYSTEM);
}
// Data publish: RETURNING system-scope exchange (vmcnt retires only after IF$
// round-trip -> pre-flag barrier orders data before flag). Proven R5.
__device__ __forceinline__ void apub8(f16* p, u64 v) {
    u64 old = __hip_atomic_exchange((u64*)p, v, __ATOMIC_RELAXED, __HIP_MEMORY_SCOPE_SYSTEM);
    asm volatile("" : : "v"(old));
}

// ---------------- prep kernels (weights -> fp16 fragment-linear) ----------------
__global__ void pack_w1(const float* __restrict__ Wih, const float* __restrict__ Whh,
                        f16* __restrict__ Wp) {
    int idx = blockIdx.x * 256 + threadIdx.x;
    if (idx >= 4*32*18*512) return;
    int j    = idx & 7;
    int lane = (idx >> 3) & 63;
    int kt   = (idx >> 9) % 18;
    int r    = (idx >> 9) / 18;
    int jt   = r & 31;
    int g    = r >> 5;
    int n = g*512 + jt*16 + (lane & 15);
    int k = kt*32 + (lane >> 4)*8 + j;
    float v = (k < 64) ? Wih[n*64 + k] : Whh[n*512 + (k - 64)];
    Wp[idx] = (f16)v;
}

__global__ void pack_w2(const float* __restrict__ Wih, const float* __restrict__ Whh,
                        f16* __restrict__ Wp) {
    int idx = blockIdx.x * 256 + threadIdx.x;
    if (idx >= 4*32*32*512) return;
    int j    = idx & 7;
    int lane = (idx >> 3) & 63;
    int kt   = (idx >> 9) & 31;
    int r    = idx >> 14;
    int jt   = r & 31;
    int g    = r >> 5;
    int n = g*512 + jt*16 + (lane & 15);
    int k = kt*32 + (lane >> 4)*8 + j;
    float v = (k < 512) ? Wih[n*512 + k] : Whh[n*512 + (k - 512)];
    Wp[idx] = (f16)v;
}

__global__ void pack_wo(const float* __restrict__ Wout, f16* __restrict__ Wp) {
    int idx = blockIdx.x * 256 + threadIdx.x;
    if (idx >= 4*16*512) return;
    int j    = idx & 7;
    int lane = (idx >> 3) & 63;
    int kt   = (idx >> 9) & 15;
    int nt   = idx >> 13;
    int n = nt*16 + (lane & 15);
    int k = kt*32 + (lane >> 4)*8 + j;
    Wp[idx] = (f16)Wout[n*512 + k];
}

__global__ void bias_sum(const float* __restrict__ a1, const float* __restrict__ b1,
                         const float* __restrict__ a2, const float* __restrict__ b2,
                         float* __restrict__ s1, float* __restrict__ s2) {
    int i = blockIdx.x * 256 + threadIdx.x;
    if (i >= 2048) return;
    s1[i] = a1[i] + b1[i];
    s2[i] = a2[i] + b2[i];
}

// ---------------- persistent self-timed kernel ----------------
// WG 0..31:  layer1 (jw = wg&15 -> cols [jw*32,jw*32+32), bh = wg>>4)
// WG 32..63: layer2 (v=wg-32: jw=v&15, bh=v>>4)
// WG 64..65: head (bh = wg-64)
// Waves: gp = w&1 (gate pair), kq = w>>1 (4-way K slice). Group size 16.
__global__ __launch_bounds__(512, 1) void lstm_persist(
    const float* __restrict__ x,
    const f16*  __restrict__ W1p,
    const f16*  __restrict__ W2p,
    const f16*  __restrict__ Wop,
    const float* __restrict__ bs1,
    const float* __restrict__ bs2,
    const float* __restrict__ bout,
    f16*  __restrict__ h1buf,   // [8][64][512] fp16
    f16*  __restrict__ h2buf,   // [8][64][512] fp16
    float* __restrict__ y,
    u32*  __restrict__ f1,      // [2][1024][16]
    u32*  __restrict__ f2,      // [2][1024][16]
    u32*  __restrict__ fH)      // [2][1024][16] (slot 0 used)
{
    __shared__ __align__(16) char smem[153600];
    float* RED = (float*)(smem + RED_OFF);
    float* CC  = (float*)(smem + CC_OFF);

    const int wg   = blockIdx.x;
    const int tid  = threadIdx.x;
    const int lane = tid & 63;
    const int w    = tid >> 6;
    const int col  = lane & 15;
    const int quad = lane >> 4;

    if (wg < 32) {
        // ================= layer 1 =================
        const int jw = wg & 15, bh = wg >> 4;
        const int gp = w & 1, kq = w >> 1;
        half8 wrx[2][2];      // [gi][jt2], kq<2 only (x k-tile = kq)
        half8 wrh[2][2][4];   // [gi][jt2][k], h k-tile = 2 + kq*4 + k
        if (kq < 2) {
            #pragma unroll
            for (int gi = 0; gi < 2; ++gi)
                #pragma unroll
                for (int jt2 = 0; jt2 < 2; ++jt2)
                    wrx[gi][jt2] = *(const half8*)(W1p + ((size_t)(((gp*2+gi)*32 + jw*2+jt2)*18 + kq)*64 + lane)*8);
        }
        #pragma unroll
        for (int gi = 0; gi < 2; ++gi)
            #pragma unroll
            for (int jt2 = 0; jt2 < 2; ++jt2)
                #pragma unroll
                for (int k = 0; k < 4; ++k)
                    wrh[gi][jt2][k] = *(const half8*)(W1p + ((size_t)(((gp*2+gi)*32 + jw*2+jt2)*18 + 2 + kq*4 + k)*64 + lane)*8);
        float bsr[4][2];
        #pragma unroll
        for (int g = 0; g < 4; ++g)
            #pragma unroll
            for (int it = 0; it < 2; ++it)
                bsr[g][it] = bs1[g*512 + jw*32 + (tid & 15) + it*16];
        CC[(tid>>4)*32 + (tid&15)]      = 0.f;
        CC[(tid>>4)*32 + (tid&15) + 16] = 0.f;

        u32* f1g = f1 + (bh << 10)*16;
        u32* f2g = f2 + (bh << 10)*16;

        for (int t = 0; t < T_; ++t) {
            const int sR = (t + SLOTS - 1) & (SLOTS-1);
            const int sW = t & (SLOTS-1);
            const int pb = t & 1;
            if (t == 0) {   // stage x[0] synchronously into buffer 0
                const int lb = tid >> 4, kc4 = tid & 15;
                const float* src = x + ((size_t)(bh*32 + lb)*T_ + 0)*(size_t)IN_ + ((kc4 ^ (lb & 7)) * 4);
                *(float4*)(smem + XS_OFF + tid*16) = *(const float4*)src;
            }
            if (w == 0) {
                if (t >= 1)     wait16(f1g + (t-1)*16, lane);      // h1[t-1] all 16 producers
                if (t >= SLOTS) wait16(f2g + (t-SLOTS)*16, lane);  // slot-reuse backpressure
            }
            __syncthreads();
            #pragma unroll
            for (int i = 0; i < 8; ++i) {   // stage h1[t-1] bh-slice (32KB)
                const int g2 = i*512 + tid;
                const int lb = g2 >> 7, r = g2 & 127, q = r >> 1, hf = r & 1;
                u64 v = aload8(h1buf + (size_t)sR*HSLOT + (size_t)(bh*32 + lb)*H_ + ((q ^ (lb & 7))*8 + hf*4));
                *(u64*)(smem + H1S_OFF + (size_t)(lb*64 + q)*16 + hf*8) = v;
            }
            __syncthreads();
            floatx4 acc[2][2][2] = {};   // [gi][m][jt2]
            #pragma unroll
            for (int m = 0; m < 2; ++m) {
                const int lb_a = m*16 + col, sw = lb_a & 7;
                if (kq < 2) {
                    const int fg = kq*8 + quad*2;
                    float4 u = *(const float4*)(smem + XS_OFF + pb*8192 + ((size_t)lb_a*16 + (fg ^ sw))*16);
                    float4 v2 = *(const float4*)(smem + XS_OFF + pb*8192 + ((size_t)lb_a*16 + ((fg+1) ^ sw))*16);
                    half8 a = (half8){(f16)u.x,(f16)u.y,(f16)u.z,(f16)u.w,
                                      (f16)v2.x,(f16)v2.y,(f16)v2.z,(f16)v2.w};
                    #pragma unroll
                    for (int gi = 0; gi < 2; ++gi)
                        #pragma unroll
                        for (int jt2 = 0; jt2 < 2; ++jt2)
                            acc[gi][m][jt2] = MFMA16(a, wrx[gi][jt2], acc[gi][m][jt2]);
                }
                #pragma unroll
                for (int k = 0; k < 4; ++k) {
                    const int kc = (kq*4 + k)*4 + quad;
                    half8 a = *(const half8*)(smem + H1S_OFF + ((size_t)lb_a*64 + (kc ^ sw))*16);
                    #pragma unroll
                    for (int gi = 0; gi < 2; ++gi)
                        #pragma unroll
                        for (int jt2 = 0; jt2 < 2; ++jt2)
                            acc[gi][m][jt2] = MFMA16(a, wrh[gi][jt2][k], acc[gi][m][jt2]);
                }
            }
            #pragma unroll
            for (int gi = 0; gi < 2; ++gi)
                #pragma unroll
                for (int m = 0; m < 2; ++m)
                    #pragma unroll
                    for (int jt2 = 0; jt2 < 2; ++jt2)
                        #pragma unroll
                        for (int r = 0; r < 4; ++r)
                            RED[kq*4096 + (gp*2+gi)*1024 + (m*16 + quad*4 + r)*32 + jt2*16 + col] = acc[gi][m][jt2][r];
            __syncthreads();
            {   // 4-way kq sum + pointwise (2 items/thread)
                const int b = tid >> 4, j0 = tid & 15;
                #pragma unroll
                for (int it = 0; it < 2; ++it) {
                    const int j = j0 + it*16;
                    float gt[4];
                    #pragma unroll
                    for (int g = 0; g < 4; ++g)
                        gt[g] = RED[        g*1024 + b*32 + j] + RED[ 4096 + g*1024 + b*32 + j]
                              + RED[ 8192 + g*1024 + b*32 + j] + RED[12288 + g*1024 + b*32 + j] + bsr[g][it];
                    const float i_ = sigmoidf_(gt[0]);
                    const float f_ = sigmoidf_(gt[1]);
                    const float g_ = tanhf_(gt[2]);
                    const float o_ = sigmoidf_(gt[3]);
                    const float cn = f_ * CC[b*32 + j] + i_ * g_;
                    CC[b*32 + j] = cn;
                    ((f16*)(smem + PUB_OFF))[b*32 + j] = (f16)(o_ * tanhf_(cn));
                }
            }
            __syncthreads();
            if (tid < 256) {   // publish 2KB slice via returning exchanges
                const int b = tid >> 3, jq = tid & 7;
                u64 v = *(const u64*)(smem + PUB_OFF + (size_t)(b*32 + jq*4)*2);
                apub8(h1buf + (size_t)sW*HSLOT + (size_t)(bh*32 + b)*H_ + jw*32 + jq*4, v);
            }
            __syncthreads();   // drain publishes
            if (tid == 0) flag_set(f1g + t*16 + jw);
            if (t + 1 < T_) {   // x prefetch (latency lands in wait window)
                const int lb = tid >> 4, kc4 = tid & 15;
                const float* src = x + ((size_t)(bh*32 + lb)*T_ + (t+1))*(size_t)IN_ + ((kc4 ^ (lb & 7)) * 4);
                *(float4*)(smem + XS_OFF + (pb^1)*8192 + tid*16) = *(const float4*)src;
            }
        }
    } else if (wg < 64) {
        // ================= layer 2 =================
        const int v = wg - 32;
        const int jw = v & 15, bh = v >> 4;
        const int gp = w & 1, kq = w >> 1;
        half8 wrA[2][2][4], wrB[2][2][4];
        #pragma unroll
        for (int gi = 0; gi < 2; ++gi)
            #pragma unroll
            for (int jt2 = 0; jt2 < 2; ++jt2)
                #pragma unroll
                for (int k = 0; k < 4; ++k) {
                    wrA[gi][jt2][k] = *(const half8*)(W2p + ((size_t)(((gp*2+gi)*32 + jw*2+jt2)*32 + kq*4 + k)*64 + lane)*8);
                    wrB[gi][jt2][k] = *(const half8*)(W2p + ((size_t)(((gp*2+gi)*32 + jw*2+jt2)*32 + 16 + kq*4 + k)*64 + lane)*8);
                }
        float bsr[4][2];
        #pragma unroll
        for (int g = 0; g < 4; ++g)
            #pragma unroll
            for (int it = 0; it < 2; ++it)
                bsr[g][it] = bs2[g*512 + jw*32 + (tid & 15) + it*16];
        CC[(tid>>4)*32 + (tid&15)]      = 0.f;
        CC[(tid>>4)*32 + (tid&15) + 16] = 0.f;

        u32* f1g = f1 + (bh << 10)*16;
        u32* f2g = f2 + (bh << 10)*16;
        u32* fHg = fH + (bh << 10)*16;

        for (int t2 = 0; t2 < T_; ++t2) {
            const int sH1 = t2 & (SLOTS-1);
            const int sRd = (t2 + SLOTS - 1) & (SLOTS-1);
            const int sW  = t2 & (SLOTS-1);
            if (w == 0) {
                wait16(f1g + t2*16, lane);                       // h1[t2] ready
                if (t2 >= SLOTS) wait1(fHg + (t2-SLOTS)*16);     // head consumed h2[t2-8]
            }
            __syncthreads();
            #pragma unroll
            for (int i = 0; i < 8; ++i) {   // stage h1[t2]
                const int g2 = i*512 + tid;
                const int lb = g2 >> 7, r = g2 & 127, q = r >> 1, hf = r & 1;
                u64 vv = aload8(h1buf + (size_t)sH1*HSLOT + (size_t)(bh*32 + lb)*H_ + ((q ^ (lb & 7))*8 + hf*4));
                *(u64*)(smem + H1S_OFF + (size_t)(lb*64 + q)*16 + hf*8) = vv;
            }
            __syncthreads();
            floatx4 acc[2][2][2] = {};
            // ---- pass A (h1 input, off critical path) ----
            #pragma unroll
            for (int m = 0; m < 2; ++m) {
                const int lb_a = m*16 + col, sw = lb_a & 7;
                #pragma unroll
                for (int k = 0; k < 4; ++k) {
                    const int kc = (kq*4 + k)*4 + quad;
                    half8 a = *(const half8*)(smem + H1S_OFF + ((size_t)lb_a*64 + (kc ^ sw))*16);
                    #pragma unroll
                    for (int gi = 0; gi < 2; ++gi)
                        #pragma unroll
                        for (int jt2 = 0; jt2 < 2; ++jt2)
                            acc[gi][m][jt2] = MFMA16(a, wrA[gi][jt2][k], acc[gi][m][jt2]);
                }
            }
            if (w == 0 && t2 >= 1) wait16(f2g + (t2-1)*16, lane);   // recurrence
            __syncthreads();
            #pragma unroll
            for (int i = 0; i < 8; ++i) {   // stage h2[t2-1]
                const int g2 = i*512 + tid;
                const int lb = g2 >> 7, r = g2 & 127, q = r >> 1, hf = r & 1;
                u64 vv = aload8(h2buf + (size_t)sRd*HSLOT + (size_t)(bh*32 + lb)*H_ + ((q ^ (lb & 7))*8 + hf*4));
                *(u64*)(smem + H2S_OFF + (size_t)(lb*64 + q)*16 + hf*8) = vv;
            }
            __syncthreads();
            // ---- pass B (h2 recurrence, critical) ----
            #pragma unroll
            for (int m = 0; m < 2; ++m) {
                const int lb_a = m*16 + col, sw = lb_a & 7;
                #pragma unroll
                for (int k = 0; k < 4; ++k) {
                    const int kc = (kq*4 + k)*4 + quad;
                    half8 a = *(const half8*)(smem + H2S_OFF + ((size_t)lb_a*64 + (kc ^ sw))*16);
                    #pragma unroll
                    for (int gi = 0; gi < 2; ++gi)
                        #pragma unroll
                        for (int jt2 = 0; jt2 < 2; ++jt2)
                            acc[gi][m][jt2] = MFMA16(a, wrB[gi][jt2][k], acc[gi][m][jt2]);
                }
            }
            #pragma unroll
            for (int gi = 0; gi < 2; ++gi)
                #pragma unroll
                for (int m = 0; m < 2; ++m)
                    #pragma unroll
                    for (int jt2 = 0; jt2 < 2; ++jt2)
                        #pragma unroll
                        for (int r = 0; r < 4; ++r)
                            RED[kq*4096 + (gp*2+gi)*1024 + (m*16 + quad*4 + r)*32 + jt2*16 + col] = acc[gi][m][jt2][r];
            __syncthreads();
            {   // 4-way kq sum + pointwise
                const int b = tid >> 4, j0 = tid & 15;
                #pragma unroll
                for (int it = 0; it < 2; ++it) {
                    const int j = j0 + it*16;
                    float gt[4];
                    #pragma unroll
                    for (int g = 0; g < 4; ++g)
                        gt[g] = RED[        g*1024 + b*32 + j] + RED[ 4096 + g*1024 + b*32 + j]
                              + RED[ 8192 + g*1024 + b*32 + j] + RED[12288 + g*1024 + b*32 + j] + bsr[g][it];
                    const float i_ = sigmoidf_(gt[0]);
                    const float f_ = sigmoidf_(gt[1]);
                    const float g_ = tanhf_(gt[2]);
                    const float o_ = sigmoidf_(gt[3]);
                    const float cn = f_ * CC[b*32 + j] + i_ * g_;
                    CC[b*32 + j] = cn;
                    ((f16*)(smem + PUB_OFF))[b*32 + j] = (f16)(o_ * tanhf_(cn));
                }
            }
            __syncthreads();
            if (tid < 256) {
                const int b = tid >> 3, jq = tid & 7;
                u64 vv = *(const u64*)(smem + PUB_OFF + (size_t)(b*32 + jq*4)*2);
                apub8(h2buf + (size_t)sW*HSLOT + (size_t)(bh*32 + b)*H_ + jw*32 + jq*4, vv);
            }
            __syncthreads();
            if (tid == 0) flag_set(f2g + t2*16 + jw);
        }
    } else {
        // ================= head =================
        const int bh = wg - 64;
        const int nt = w & 3, kh = w >> 2;
        half8 wr[8];
        #pragma unroll
        for (int k = 0; k < 8; ++k)
            wr[k] = *(const half8*)(Wop + ((size_t)(nt*16 + kh*8 + k)*64 + lane)*8);
        const float boutr = bout[nt*16 + col];
        u32* f2g = f2 + (bh << 10)*16;
        u32* fHg = fH + (bh << 10)*16;
        const int lb0 = col, lb1 = 16 + col;
        const int swz = col & 7;

        for (int t3 = 0; t3 < T_; ++t3) {
            const int sH = t3 & (SLOTS-1);
            if (w == 0) wait16(f2g + t3*16, lane);
            __syncthreads();
            #pragma unroll
            for (int i = 0; i < 8; ++i) {   // stage h2[t3]
                const int g2 = i*512 + tid;
                const int lb = g2 >> 7, r = g2 & 127, q = r >> 1, hf = r & 1;
                u64 vv = aload8(h2buf + (size_t)sH*HSLOT + (size_t)(bh*32 + lb)*H_ + ((q ^ (lb & 7))*8 + hf*4));
                *(u64*)(smem + H1S_OFF + (size_t)(lb*64 + q)*16 + hf*8) = vv;
            }
            __syncthreads();   // staging drained -> release back-pressure
            if (tid == 0) flag_set(fHg + t3*16);
            floatx4 acc0 = {0.f,0.f,0.f,0.f}, acc1 = {0.f,0.f,0.f,0.f};
            #pragma unroll
            for (int k = 0; k < 8; ++k) {
                const int kc = (kh*8 + k)*4 + quad;
                half8 a0 = *(const half8*)(smem + H1S_OFF + ((size_t)lb0*64 + (kc ^ swz))*16);
                half8 a1v = *(const half8*)(smem + H1S_OFF + ((size_t)lb1*64 + (kc ^ swz))*16);
                acc0 = MFMA16(a0,  wr[k], acc0);
                acc1 = MFMA16(a1v, wr[k], acc1);
            }
            if (kh == 1) {
                #pragma unroll
                for (int r = 0; r < 4; ++r) {
                    RED[(nt*2+0)*256 + (quad*4 + r)*16 + col] = acc0[r];
                    RED[(nt*2+1)*256 + (quad*4 + r)*16 + col] = acc1[r];
                }
            }
            __syncthreads();
            if (kh == 0) {
                #pragma unroll
                for (int r = 0; r < 4; ++r) {
                    const float v0 = acc0[r] + RED[(nt*2+0)*256 + (quad*4 + r)*16 + col] + boutr;
                    const float v1 = acc1[r] + RED[(nt*2+1)*256 + (quad*4 + r)*16 + col] + boutr;
                    const int b0 = bh*32 +  0 + quad*4 + r;
                    const int b1 = bh*32 + 16 + quad*4 + r;
                    y[((size_t)b0*T_ + t3)*OUT_ + nt*16 + col] = v0;
                    y[((size_t)b1*T_ + t3)*OUT_ + nt*16 + col] = v1;
                }
            }
            __syncthreads();   // RED reuse next step
        }
    }
}

// ---------------- launch ----------------
extern "C" void kernel_launch(void* const* d_in, const int* in_sizes, int n_in,
                              void* d_out, int out_size, void* d_ws, size_t ws_size,
                              hipStream_t stream) {
    const float* x    = (const float*)d_in[0];
    const float* Wih1 = (const float*)d_in[1];
    const float* Whh1 = (const float*)d_in[2];
    const float* bih1 = (const float*)d_in[3];
    const float* bhh1 = (const float*)d_in[4];
    const float* Wih2 = (const float*)d_in[5];
    const float* Whh2 = (const float*)d_in[6];
    const float* bih2 = (const float*)d_in[7];
    const float* bhh2 = (const float*)d_in[8];
    const float* Wout = (const float*)d_in[9];
    const float* bout = (const float*)d_in[10];
    float* y = (float*)d_out;

    char* ws = (char*)d_ws;
    f16*   W1p   = (f16*)(ws + 0);           // 2,359,296 B
    f16*   W2p   = (f16*)(ws + 2359296);     // 4,194,304 B
    f16*   Wop   = (f16*)(ws + 6553600);     //    65,536 B
    float* bs1   = (float*)(ws + 6619136);   //     8,192 B
    float* bs2   = (float*)(ws + 6627328);   //     8,192 B
    f16*   h1buf = (f16*)(ws + 6635520);     // 8 slots = 524,288 B
    f16*   h2buf = (f16*)(ws + 7159808);     // 8 slots = 524,288 B
    u32*   f1    = (u32*)(ws + 7684096);     //   131,072 B
    u32*   f2    = (u32*)(ws + 7815168);     //   131,072 B
    u32*   fH    = (u32*)(ws + 7946240);     //   131,072 B

    // zero h slots (t=-1 state in slot 7) + all flags
    hipMemsetAsync(ws + 6635520, 0, 1441792, stream);

    pack_w1<<<4608, 256, 0, stream>>>(Wih1, Whh1, W1p);
    pack_w2<<<8192, 256, 0, stream>>>(Wih2, Whh2, W2p);
    pack_wo<<<128, 256, 0, stream>>>(Wout, Wop);
    bias_sum<<<8, 256, 0, stream>>>(bih1, bhh1, bih2, bhh2, bs1, bs2);

    lstm_persist<<<NWG, 512, 0, stream>>>(x, W1p, W2p, Wop, bs1, bs2, bout,
                                          h1buf, h2buf, y, f1, f2, fH);
}